// Round 1
// baseline (1504.736 us; speedup 1.0000x reference)
//
#include <hip/hip_runtime.h>

#define DFEAT 64

// ---------------------------------------------------------------------------
// Degree: deg[dst] += 1 over all edges (edge_index constant across layers,
// so this runs once per call).
// ---------------------------------------------------------------------------
__global__ void __launch_bounds__(256)
deg_kernel(const int* __restrict__ dst, float* __restrict__ deg, int E) {
    int e = blockIdx.x * 256 + threadIdx.x;
    if (e < E) atomicAdd(&deg[dst[e]], 1.0f);
}

// ---------------------------------------------------------------------------
// Scatter-add: msg[dst[e]][f] += x[src[e]][f].  One wave per edge, lane = f.
// Gather (256B) and atomics (64x4B contiguous) are coalesced; x/msg are
// L2/L3 resident (25.6 MB each).
// ---------------------------------------------------------------------------
__global__ void __launch_bounds__(256)
scatter_kernel(const float* __restrict__ x, const int* __restrict__ srcs,
               const int* __restrict__ dsts, float* __restrict__ msg, int E) {
    int wid  = (blockIdx.x * 256 + threadIdx.x) >> 6;   // edge id
    int lane = threadIdx.x & 63;                        // feature id
    if (wid < E) {
        int s = srcs[wid];
        int d = dsts[wid];
        float v = x[(size_t)s * DFEAT + lane];
        atomicAdd(&msg[(size_t)d * DFEAT + lane], v);
    }
}

// ---------------------------------------------------------------------------
// Per-node transform: mean = msg/max(deg,1); out = mean@Wl.T + bl + x@Wr.T;
// L2-normalize; ReLU; write h (or fused batch-sum readout for final layer).
// One wave per node, lane = output dim. Weights in LDS, stride 68 floats
// (16B-aligned, conflict-free float4 phases). Node features staged in
// per-wave LDS, read back as wave-broadcasts (free).
// ---------------------------------------------------------------------------
__global__ void __launch_bounds__(256)
transform_kernel(const float* __restrict__ x, const float* __restrict__ msg,
                 const float* __restrict__ deg,
                 const float* __restrict__ Wl, const float* __restrict__ bl,
                 const float* __restrict__ Wr,
                 float* __restrict__ h_out,
                 const int* __restrict__ batch, float* __restrict__ out,
                 int n_nodes, int final_layer) {
    constexpr int WS = DFEAT + 4;  // 68: 16B-aligned rows, conflict-free b128
    __shared__ float WlL[DFEAT * WS];
    __shared__ float WrL[DFEAT * WS];
    __shared__ float feat[4][2 * DFEAT];   // per-wave: [mean | x]

    // stage weights
    for (int t = threadIdx.x; t < DFEAT * DFEAT; t += 256) {
        int r = t >> 6, c = t & 63;
        WlL[r * WS + c] = Wl[t];
        WrL[r * WS + c] = Wr[t];
    }
    __syncthreads();

    const int wib  = threadIdx.x >> 6;
    const int lane = threadIdx.x & 63;
    float* fm = feat[wib];
    const float4* wl4 = reinterpret_cast<const float4*>(&WlL[lane * WS]);
    const float4* wr4 = reinterpret_cast<const float4*>(&WrL[lane * WS]);
    const float4* fm4 = reinterpret_cast<const float4*>(fm);

    const float blv = bl[lane];

    const int nwaves = gridDim.x * 4;
    const int gwave  = blockIdx.x * 4 + wib;
    const int iters  = (n_nodes + nwaves - 1) / nwaves;  // uniform trip count

    for (int it = 0; it < iters; ++it) {
        int n = gwave + it * nwaves;
        bool act = (n < n_nodes);

        if (act) {
            float dg  = deg[n];
            float inv = dg > 0.0f ? 1.0f / dg : 0.0f;  // max(deg,1); msg==0 if deg==0
            fm[lane]         = msg[(size_t)n * DFEAT + lane] * inv;
            fm[DFEAT + lane] = x[(size_t)n * DFEAT + lane];
        }
        __syncthreads();   // publish feat within block (uniform trip count)

        if (act) {
            float acc = blv;
#pragma unroll
            for (int j = 0; j < DFEAT / 4; j++) {
                float4 w1 = wl4[j];
                float4 w2 = wr4[j];
                float4 f1 = fm4[j];                 // broadcast reads
                float4 f2 = fm4[DFEAT / 4 + j];
                acc += f1.x * w1.x + f1.y * w1.y + f1.z * w1.z + f1.w * w1.w;
                acc += f2.x * w2.x + f2.y * w2.y + f2.z * w2.z + f2.w * w2.w;
            }
            // L2 norm across the 64 output lanes
            float ss = acc * acc;
#pragma unroll
            for (int off = 32; off; off >>= 1) ss += __shfl_xor(ss, off, 64);
            float nrm = sqrtf(ss);
            float o = acc / fmaxf(nrm, 1e-12f);
            o = fmaxf(o, 0.0f);   // ReLU (applied after every layer)
            if (final_layer) {
                atomicAdd(&out[(size_t)batch[n] * DFEAT + lane], o);
            } else {
                h_out[(size_t)n * DFEAT + lane] = o;
            }
        }
        __syncthreads();   // protect feat before next iteration's writes
    }
}

// ---------------------------------------------------------------------------
extern "C" void kernel_launch(void* const* d_in, const int* in_sizes, int n_in,
                              void* d_out, int out_size, void* d_ws, size_t ws_size,
                              hipStream_t stream) {
    const float* x_raw = (const float*)d_in[0];
    const int*   eidx  = (const int*)d_in[1];
    const int*   batch = (const int*)d_in[2];
    const float* Wl0 = (const float*)d_in[3];
    const float* bl0 = (const float*)d_in[4];
    const float* Wr0 = (const float*)d_in[5];
    const float* Wl1 = (const float*)d_in[6];
    const float* bl1 = (const float*)d_in[7];
    const float* Wr1 = (const float*)d_in[8];
    const float* Wl2 = (const float*)d_in[9];
    const float* bl2 = (const float*)d_in[10];
    const float* Wr2 = (const float*)d_in[11];

    const int N = in_sizes[0] / DFEAT;
    const int E = in_sizes[1] / 2;
    const int*   srcs = eidx;
    const int*   dsts = eidx + E;
    float* out = (float*)d_out;

    // workspace layout
    char* ws = (char*)d_ws;
    size_t degB  = ((size_t)N * 4 + 511) & ~(size_t)511;
    size_t featB = ((size_t)N * DFEAT * 4 + 511) & ~(size_t)511;
    float* deg = (float*)ws;
    float* msg = (float*)(ws + degB);
    float* hA  = (float*)(ws + degB + featB);
    float* hB  = (float*)(ws + degB + 2 * featB);

    // zero accumulators (ws/d_out are poisoned each call)
    hipMemsetAsync(deg, 0, (size_t)N * 4, stream);
    hipMemsetAsync(msg, 0, (size_t)N * DFEAT * 4, stream);
    hipMemsetAsync(out, 0, (size_t)out_size * 4, stream);

    const int degBlocks  = (E + 255) / 256;
    const int scatBlocks = (E + 3) / 4;          // one wave per edge
    const int xfBlocks   = 2048;                 // grid-stride over nodes

    deg_kernel<<<degBlocks, 256, 0, stream>>>(dsts, deg, E);

    // ---- layer 0: x_raw -> hA
    scatter_kernel<<<scatBlocks, 256, 0, stream>>>(x_raw, srcs, dsts, msg, E);
    transform_kernel<<<xfBlocks, 256, 0, stream>>>(x_raw, msg, deg, Wl0, bl0, Wr0,
                                                   hA, nullptr, nullptr, N, 0);
    hipMemsetAsync(msg, 0, (size_t)N * DFEAT * 4, stream);

    // ---- layer 1: hA -> hB
    scatter_kernel<<<scatBlocks, 256, 0, stream>>>(hA, srcs, dsts, msg, E);
    transform_kernel<<<xfBlocks, 256, 0, stream>>>(hA, msg, deg, Wl1, bl1, Wr1,
                                                   hB, nullptr, nullptr, N, 0);
    hipMemsetAsync(msg, 0, (size_t)N * DFEAT * 4, stream);

    // ---- layer 2: hB -> (fused batch-sum readout into d_out)
    scatter_kernel<<<scatBlocks, 256, 0, stream>>>(hB, srcs, dsts, msg, E);
    transform_kernel<<<xfBlocks, 256, 0, stream>>>(hB, msg, deg, Wl2, bl2, Wr2,
                                                   nullptr, batch, out, N, 1);
}

// Round 2
// 795.961 us; speedup vs baseline: 1.8905x; 1.8905x over previous
//
#include <hip/hip_runtime.h>

#define DFEAT 64

// ============================================================================
// CSR build (edge_index is constant across layers -> build once per call)
// ============================================================================

__global__ void __launch_bounds__(256)
deg_count_kernel(const int* __restrict__ dsts, int* __restrict__ degi, int E) {
    int e = blockIdx.x * 256 + threadIdx.x;
    if (e < E) atomicAdd(&degi[dsts[e]], 1);
}

// per-1024-chunk sums for the scan
__global__ void __launch_bounds__(1024)
block_sum_kernel(const int* __restrict__ degi, int* __restrict__ bsum, int N) {
    __shared__ int sm[1024];
    int idx = blockIdx.x * 1024 + threadIdx.x;
    sm[threadIdx.x] = (idx < N) ? degi[idx] : 0;
    __syncthreads();
    for (int s = 512; s > 0; s >>= 1) {
        if (threadIdx.x < s) sm[threadIdx.x] += sm[threadIdx.x + s];
        __syncthreads();
    }
    if (threadIdx.x == 0) bsum[blockIdx.x] = sm[0];
}

// tiny serial exclusive scan of ~98 block sums
__global__ void __launch_bounds__(64)
scan_bsum_kernel(int* __restrict__ bsum, int nb) {
    if (threadIdx.x == 0 && blockIdx.x == 0) {
        int run = 0;
        for (int i = 0; i < nb; ++i) { int v = bsum[i]; bsum[i] = run; run += v; }
    }
}

// in-chunk Hillis-Steele inclusive scan + chunk offset -> rowptr & cursor
__global__ void __launch_bounds__(1024)
scan_final_kernel(const int* __restrict__ degi, const int* __restrict__ bsum,
                  int* __restrict__ rowptr, int* __restrict__ cursor, int N) {
    __shared__ int sm[1024];
    int idx = blockIdx.x * 1024 + threadIdx.x;
    int v = (idx < N) ? degi[idx] : 0;
    sm[threadIdx.x] = v;
    __syncthreads();
    for (int s = 1; s < 1024; s <<= 1) {
        int t = (threadIdx.x >= s) ? sm[threadIdx.x - s] : 0;
        __syncthreads();
        sm[threadIdx.x] += t;
        __syncthreads();
    }
    int excl = bsum[blockIdx.x] + sm[threadIdx.x] - v;
    if (idx < N) { rowptr[idx] = excl; cursor[idx] = excl; }
    if (idx == N - 1) rowptr[N] = excl + v;   // == E
}

__global__ void __launch_bounds__(256)
fill_kernel(const int* __restrict__ srcs, const int* __restrict__ dsts,
            int* __restrict__ cursor, int* __restrict__ col, int E) {
    int e = blockIdx.x * 256 + threadIdx.x;
    if (e < E) {
        int pos = atomicAdd(&cursor[dsts[e]], 1);
        col[pos] = srcs[e];
    }
}

// ============================================================================
// Fused SAGE layer: CSR gather-mean + (mean@Wl.T + bl + x@Wr.T) + L2norm +
// ReLU + (h_out store | fused batch-sum readout).
// One wave per node-PAIR (lane = feature/output dim): amortizes the LDS
// weight reads across 2 nodes. Neighbor ids broadcast via __shfl; gather
// unrolled x4 for 4 outstanding 256B loads per node chain.
// ============================================================================
__global__ void __launch_bounds__(256)
sage_layer_kernel(const float* __restrict__ x,
                  const int* __restrict__ rowptr, const int* __restrict__ col,
                  const float* __restrict__ Wl, const float* __restrict__ bl,
                  const float* __restrict__ Wr,
                  float* __restrict__ h_out,
                  const int* __restrict__ batch, float* __restrict__ out,
                  int n_nodes, int final_layer) {
    constexpr int WS = DFEAT + 4;  // 68: 16B-aligned rows; b128 lanes spread evenly over bank groups
    __shared__ float WlL[DFEAT * WS];
    __shared__ float WrL[DFEAT * WS];
    __shared__ float feat[4][4 * DFEAT];   // per-wave: [meanA | xA | meanB | xB]

    for (int t = threadIdx.x; t < DFEAT * DFEAT; t += 256) {
        int r = t >> 6, c = t & 63;
        WlL[r * WS + c] = Wl[t];
        WrL[r * WS + c] = Wr[t];
    }
    __syncthreads();

    const int wib  = threadIdx.x >> 6;
    const int lane = threadIdx.x & 63;
    float* fm = feat[wib];
    const float4* wl4 = reinterpret_cast<const float4*>(&WlL[lane * WS]);
    const float4* wr4 = reinterpret_cast<const float4*>(&WrL[lane * WS]);
    const float4* fm4 = reinterpret_cast<const float4*>(fm);
    const float blv = bl[lane];

    const int P      = (n_nodes + 1) >> 1;       // node pairs
    const int nwaves = gridDim.x * 4;
    const int gwave  = blockIdx.x * 4 + wib;
    const int iters  = (P + nwaves - 1) / nwaves;  // uniform trip count (block barriers below)

    for (int it = 0; it < iters; ++it) {
        int p  = gwave + it * nwaves;
        bool actp = (p < P);
        int n0 = 2 * p, n1 = 2 * p + 1;
        bool act1 = actp && (n1 < n_nodes);

        if (actp) {
            // ---- gather node n0
            int st0 = rowptr[n0], en0 = rowptr[n0 + 1];
            float s0 = 0.0f;
            for (int base = st0; base < en0; base += 64) {
                int cnt = min(64, en0 - base);
                int nb = (lane < cnt) ? col[base + lane] : 0;
                int i = 0;
                for (; i + 4 <= cnt; i += 4) {
                    int j0 = __shfl(nb, i, 64),     j1 = __shfl(nb, i + 1, 64);
                    int j2 = __shfl(nb, i + 2, 64), j3 = __shfl(nb, i + 3, 64);
                    float v0 = x[(size_t)j0 * DFEAT + lane];
                    float v1 = x[(size_t)j1 * DFEAT + lane];
                    float v2 = x[(size_t)j2 * DFEAT + lane];
                    float v3 = x[(size_t)j3 * DFEAT + lane];
                    s0 += (v0 + v1) + (v2 + v3);
                }
                for (; i < cnt; ++i) {
                    int j = __shfl(nb, i, 64);
                    s0 += x[(size_t)j * DFEAT + lane];
                }
            }
            float d0 = (float)(en0 - st0);
            fm[lane]         = (d0 > 0.0f) ? s0 / d0 : 0.0f;
            fm[DFEAT + lane] = x[(size_t)n0 * DFEAT + lane];

            // ---- gather node n1
            float s1 = 0.0f;
            float d1 = 0.0f;
            if (act1) {
                int st1 = rowptr[n1], en1 = rowptr[n1 + 1];
                for (int base = st1; base < en1; base += 64) {
                    int cnt = min(64, en1 - base);
                    int nb = (lane < cnt) ? col[base + lane] : 0;
                    int i = 0;
                    for (; i + 4 <= cnt; i += 4) {
                        int j0 = __shfl(nb, i, 64),     j1 = __shfl(nb, i + 1, 64);
                        int j2 = __shfl(nb, i + 2, 64), j3 = __shfl(nb, i + 3, 64);
                        float v0 = x[(size_t)j0 * DFEAT + lane];
                        float v1 = x[(size_t)j1 * DFEAT + lane];
                        float v2 = x[(size_t)j2 * DFEAT + lane];
                        float v3 = x[(size_t)j3 * DFEAT + lane];
                        s1 += (v0 + v1) + (v2 + v3);
                    }
                    for (; i < cnt; ++i) {
                        int j = __shfl(nb, i, 64);
                        s1 += x[(size_t)j * DFEAT + lane];
                    }
                }
                d1 = (float)(en1 - st1);
            }
            fm[2 * DFEAT + lane] = (d1 > 0.0f) ? s1 / d1 : 0.0f;
            fm[3 * DFEAT + lane] = act1 ? x[(size_t)n1 * DFEAT + lane] : 0.0f;
        }
        __syncthreads();   // publish feat (uniform trip count)

        if (actp) {
            float accA = blv, accB = blv;
#pragma unroll
            for (int j = 0; j < DFEAT / 4; ++j) {
                float4 w1 = wl4[j];
                float4 w2 = wr4[j];
                float4 a1 = fm4[j];
                float4 a2 = fm4[16 + j];
                float4 b1 = fm4[32 + j];
                float4 b2 = fm4[48 + j];
                accA += a1.x * w1.x + a1.y * w1.y + a1.z * w1.z + a1.w * w1.w
                      + a2.x * w2.x + a2.y * w2.y + a2.z * w2.z + a2.w * w2.w;
                accB += b1.x * w1.x + b1.y * w1.y + b1.z * w1.z + b1.w * w1.w
                      + b2.x * w2.x + b2.y * w2.y + b2.z * w2.z + b2.w * w2.w;
            }
            float ssA = accA * accA, ssB = accB * accB;
#pragma unroll
            for (int off = 32; off; off >>= 1) {
                ssA += __shfl_xor(ssA, off, 64);
                ssB += __shfl_xor(ssB, off, 64);
            }
            float oA = fmaxf(accA / fmaxf(sqrtf(ssA), 1e-12f), 0.0f);
            float oB = fmaxf(accB / fmaxf(sqrtf(ssB), 1e-12f), 0.0f);

            if (final_layer) {
                atomicAdd(&out[(size_t)batch[n0] * DFEAT + lane], oA);
                if (act1) atomicAdd(&out[(size_t)batch[n1] * DFEAT + lane], oB);
            } else {
                h_out[(size_t)n0 * DFEAT + lane] = oA;
                if (act1) h_out[(size_t)n1 * DFEAT + lane] = oB;
            }
        }
        __syncthreads();   // protect feat before next iteration
    }
}

// ============================================================================
extern "C" void kernel_launch(void* const* d_in, const int* in_sizes, int n_in,
                              void* d_out, int out_size, void* d_ws, size_t ws_size,
                              hipStream_t stream) {
    const float* x_raw = (const float*)d_in[0];
    const int*   eidx  = (const int*)d_in[1];
    const int*   batch = (const int*)d_in[2];
    const float* Wl0 = (const float*)d_in[3];
    const float* bl0 = (const float*)d_in[4];
    const float* Wr0 = (const float*)d_in[5];
    const float* Wl1 = (const float*)d_in[6];
    const float* bl1 = (const float*)d_in[7];
    const float* Wr1 = (const float*)d_in[8];
    const float* Wl2 = (const float*)d_in[9];
    const float* bl2 = (const float*)d_in[10];
    const float* Wr2 = (const float*)d_in[11];

    const int N = in_sizes[0] / DFEAT;
    const int E = in_sizes[1] / 2;
    const int* srcs = eidx;
    const int* dsts = eidx + E;
    float* out = (float*)d_out;

    const int nb = (N + 1023) / 1024;   // scan chunks

    // workspace layout
    char* ws = (char*)d_ws;
    auto align512 = [](size_t v) { return (v + 511) & ~(size_t)511; };
    size_t off = 0;
    int* degi   = (int*)(ws + off); off += align512((size_t)N * 4);
    int* rowptr = (int*)(ws + off); off += align512(((size_t)N + 1) * 4);
    int* cursor = (int*)(ws + off); off += align512((size_t)N * 4);
    int* bsum   = (int*)(ws + off); off += align512((size_t)nb * 4);
    int* col    = (int*)(ws + off); off += align512((size_t)E * 4);
    float* hA   = (float*)(ws + off); off += align512((size_t)N * DFEAT * 4);
    float* hB   = (float*)(ws + off);

    hipMemsetAsync(degi, 0, (size_t)N * 4, stream);
    hipMemsetAsync(out, 0, (size_t)out_size * 4, stream);

    // ---- CSR build (once; reused by all 3 layers)
    deg_count_kernel<<<(E + 255) / 256, 256, 0, stream>>>(dsts, degi, E);
    block_sum_kernel<<<nb, 1024, 0, stream>>>(degi, bsum, N);
    scan_bsum_kernel<<<1, 64, 0, stream>>>(bsum, nb);
    scan_final_kernel<<<nb, 1024, 0, stream>>>(degi, bsum, rowptr, cursor, N);
    fill_kernel<<<(E + 255) / 256, 256, 0, stream>>>(srcs, dsts, cursor, col, E);

    const int layerBlocks = 1024;   // 4 blocks/CU (LDS-limited), grid-stride over node pairs

    // ---- layer 0: x_raw -> hA
    sage_layer_kernel<<<layerBlocks, 256, 0, stream>>>(x_raw, rowptr, col,
        Wl0, bl0, Wr0, hA, nullptr, nullptr, N, 0);
    // ---- layer 1: hA -> hB
    sage_layer_kernel<<<layerBlocks, 256, 0, stream>>>(hA, rowptr, col,
        Wl1, bl1, Wr1, hB, nullptr, nullptr, N, 0);
    // ---- layer 2: hB -> out (fused batch-sum readout)
    sage_layer_kernel<<<layerBlocks, 256, 0, stream>>>(hB, rowptr, col,
        Wl2, bl2, Wr2, nullptr, batch, out, N, 1);
}

// Round 3
// 725.735 us; speedup vs baseline: 2.0734x; 1.0968x over previous
//
#include <hip/hip_runtime.h>

#define DFEAT 64

// ============================================================================
// CSR build (edge_index constant across layers -> build once per call)
// ============================================================================

__global__ void __launch_bounds__(256)
deg_count_kernel(const int* __restrict__ dsts, int* __restrict__ degi, int E) {
    int e = blockIdx.x * 256 + threadIdx.x;
    if (e < E) atomicAdd(&degi[dsts[e]], 1);
}

__global__ void __launch_bounds__(1024)
block_sum_kernel(const int* __restrict__ degi, int* __restrict__ bsum, int N) {
    __shared__ int sm[1024];
    int idx = blockIdx.x * 1024 + threadIdx.x;
    sm[threadIdx.x] = (idx < N) ? degi[idx] : 0;
    __syncthreads();
    for (int s = 512; s > 0; s >>= 1) {
        if (threadIdx.x < s) sm[threadIdx.x] += sm[threadIdx.x + s];
        __syncthreads();
    }
    if (threadIdx.x == 0) bsum[blockIdx.x] = sm[0];
}

__global__ void __launch_bounds__(64)
scan_bsum_kernel(int* __restrict__ bsum, int nb) {
    if (threadIdx.x == 0 && blockIdx.x == 0) {
        int run = 0;
        for (int i = 0; i < nb; ++i) { int v = bsum[i]; bsum[i] = run; run += v; }
    }
}

__global__ void __launch_bounds__(1024)
scan_final_kernel(const int* __restrict__ degi, const int* __restrict__ bsum,
                  int* __restrict__ rowptr, int* __restrict__ cursor, int N) {
    __shared__ int sm[1024];
    int idx = blockIdx.x * 1024 + threadIdx.x;
    int v = (idx < N) ? degi[idx] : 0;
    sm[threadIdx.x] = v;
    __syncthreads();
    for (int s = 1; s < 1024; s <<= 1) {
        int t = (threadIdx.x >= s) ? sm[threadIdx.x - s] : 0;
        __syncthreads();
        sm[threadIdx.x] += t;
        __syncthreads();
    }
    int excl = bsum[blockIdx.x] + sm[threadIdx.x] - v;
    if (idx < N) { rowptr[idx] = excl; cursor[idx] = excl; }
    if (idx == N - 1) rowptr[N] = excl + v;   // == E
}

__global__ void __launch_bounds__(256)
fill_kernel(const int* __restrict__ srcs, const int* __restrict__ dsts,
            int* __restrict__ cursor, int* __restrict__ col, int E) {
    int e = blockIdx.x * 256 + threadIdx.x;
    if (e < E) {
        int pos = atomicAdd(&cursor[dsts[e]], 1);
        col[pos] = srcs[e];
    }
}

// ============================================================================
// Fused SAGE layer, vectorized gather edition.
// Gather lane map: r = lane>>4 (neighbor slot 0..3), c = lane&15 (float4
// chunk). One wave instruction loads 4 neighbor rows (4 KB); unroll x4 puts
// 16 rows (16 KB logical) in flight per node. Cross-r sum via shfl_xor(16,32).
// Transform: lane = output dim, weights in LDS (stride 68), feat rows in
// per-wave LDS read as broadcasts.
// ============================================================================
__global__ void __launch_bounds__(256)
sage_layer_kernel(const float* __restrict__ x,
                  const int* __restrict__ rowptr, const int* __restrict__ col,
                  const float* __restrict__ Wl, const float* __restrict__ bl,
                  const float* __restrict__ Wr,
                  float* __restrict__ h_out,
                  const int* __restrict__ batch, float* __restrict__ out,
                  int n_nodes, int final_layer) {
    constexpr int WS = DFEAT + 4;  // 68 floats: 16B-aligned rows
    __shared__ float WlL[DFEAT * WS];
    __shared__ float WrL[DFEAT * WS];
    __shared__ float feat[4][4 * DFEAT];   // per-wave: [meanA | xA | meanB | xB]

    for (int t = threadIdx.x; t < DFEAT * DFEAT; t += 256) {
        int rr = t >> 6, cc = t & 63;
        WlL[rr * WS + cc] = Wl[t];
        WrL[rr * WS + cc] = Wr[t];
    }
    __syncthreads();

    const int wib  = threadIdx.x >> 6;
    const int lane = threadIdx.x & 63;
    const int r    = lane >> 4;      // neighbor slot within group of 4
    const int c    = lane & 15;      // float4 chunk of the 64-feat row
    float* fm = feat[wib];
    float4* fmv = reinterpret_cast<float4*>(fm);
    const float4* x4 = reinterpret_cast<const float4*>(x);
    const float4* wl4 = reinterpret_cast<const float4*>(&WlL[lane * WS]);
    const float4* wr4 = reinterpret_cast<const float4*>(&WrL[lane * WS]);
    const float4* fm4 = reinterpret_cast<const float4*>(fm);
    const float blv = bl[lane];

    const int P      = (n_nodes + 1) >> 1;
    const int nwaves = gridDim.x * 4;
    const int gwave  = blockIdx.x * 4 + wib;
    const int iters  = (P + nwaves - 1) / nwaves;   // uniform trip count

    for (int it = 0; it < iters; ++it) {
        int p = gwave + it * nwaves;
        bool actp = (p < P);
        int n0 = 2 * p, n1 = 2 * p + 1;
        bool act1 = actp && (n1 < n_nodes);

        if (actp) {
            // row pointers: n1 starts where n0 ends
            int st0 = rowptr[n0];
            int en0 = rowptr[n0 + 1];
            int en1 = act1 ? rowptr[n0 + 2] : en0;

            // root rows (issue early; consumed at LDS-write time)
            float4 root0 = x4[(size_t)n0 * 16 + c];
            float4 root1 = act1 ? x4[(size_t)n1 * 16 + c] : make_float4(0, 0, 0, 0);

            // ---- gather mean for a node: 4 rows per instruction, x4 unrolled
            auto gather = [&](int st, int en) -> float4 {
                float4 a; a.x = a.y = a.z = a.w = 0.0f;
                for (int base = st; base < en; base += 64) {
                    int cc = min(64, en - base);
                    int nb = (lane < cc) ? col[base + lane] : 0;
                    for (int step = 0; step < cc; step += 16) {
                        int rem = cc - step;
                        if (rem >= 16) {
                            int q0 = __shfl(nb, step + r, 64);
                            int q1 = __shfl(nb, step + 4 + r, 64);
                            int q2 = __shfl(nb, step + 8 + r, 64);
                            int q3 = __shfl(nb, step + 12 + r, 64);
                            float4 v0 = x4[(size_t)q0 * 16 + c];
                            float4 v1 = x4[(size_t)q1 * 16 + c];
                            float4 v2 = x4[(size_t)q2 * 16 + c];
                            float4 v3 = x4[(size_t)q3 * 16 + c];
                            a.x += (v0.x + v1.x) + (v2.x + v3.x);
                            a.y += (v0.y + v1.y) + (v2.y + v3.y);
                            a.z += (v0.z + v1.z) + (v2.z + v3.z);
                            a.w += (v0.w + v1.w) + (v2.w + v3.w);
                        } else {
#pragma unroll
                            for (int k = 0; k < 4; ++k) {
                                int qi = step + 4 * k + r;
                                if (qi < cc) {
                                    int q = __shfl(nb, qi, 64);
                                    float4 v = x4[(size_t)q * 16 + c];
                                    a.x += v.x; a.y += v.y; a.z += v.z; a.w += v.w;
                                }
                            }
                        }
                    }
                }
                return a;
            };

            float4 s0 = gather(st0, en0);
            float4 s1 = act1 ? gather(en0, en1) : make_float4(0, 0, 0, 0);

            // reduce across the 4 neighbor slots (lanes differing in bits 4,5)
#pragma unroll
            for (int off = 16; off <= 32; off <<= 1) {
                s0.x += __shfl_xor(s0.x, off, 64);
                s0.y += __shfl_xor(s0.y, off, 64);
                s0.z += __shfl_xor(s0.z, off, 64);
                s0.w += __shfl_xor(s0.w, off, 64);
                s1.x += __shfl_xor(s1.x, off, 64);
                s1.y += __shfl_xor(s1.y, off, 64);
                s1.z += __shfl_xor(s1.z, off, 64);
                s1.w += __shfl_xor(s1.w, off, 64);
            }
            float d0 = (float)(en0 - st0);
            float d1 = (float)(en1 - en0);
            float i0 = d0 > 0.0f ? 1.0f / d0 : 0.0f;
            float i1 = d1 > 0.0f ? 1.0f / d1 : 0.0f;

            if (r == 0) {          // mean rows
                float4 m0; m0.x = s0.x * i0; m0.y = s0.y * i0; m0.z = s0.z * i0; m0.w = s0.w * i0;
                float4 m1; m1.x = s1.x * i1; m1.y = s1.y * i1; m1.z = s1.z * i1; m1.w = s1.w * i1;
                fmv[c]      = m0;
                fmv[32 + c] = m1;
            } else if (r == 1) {   // root rows
                fmv[16 + c] = root0;
                fmv[48 + c] = root1;
            }
        }
        __syncthreads();   // publish feat (uniform trip count)

        if (actp) {
            float accA = blv, accB = blv;
#pragma unroll
            for (int j = 0; j < DFEAT / 4; ++j) {
                float4 w1 = wl4[j];
                float4 w2 = wr4[j];
                float4 a1 = fm4[j];        // broadcasts
                float4 a2 = fm4[16 + j];
                float4 b1 = fm4[32 + j];
                float4 b2 = fm4[48 + j];
                accA += a1.x * w1.x + a1.y * w1.y + a1.z * w1.z + a1.w * w1.w
                      + a2.x * w2.x + a2.y * w2.y + a2.z * w2.z + a2.w * w2.w;
                accB += b1.x * w1.x + b1.y * w1.y + b1.z * w1.z + b1.w * w1.w
                      + b2.x * w2.x + b2.y * w2.y + b2.z * w2.z + b2.w * w2.w;
            }
            float ssA = accA * accA, ssB = accB * accB;
#pragma unroll
            for (int off = 32; off; off >>= 1) {
                ssA += __shfl_xor(ssA, off, 64);
                ssB += __shfl_xor(ssB, off, 64);
            }
            float oA = fmaxf(accA / fmaxf(sqrtf(ssA), 1e-12f), 0.0f);
            float oB = fmaxf(accB / fmaxf(sqrtf(ssB), 1e-12f), 0.0f);

            if (final_layer) {
                atomicAdd(&out[(size_t)batch[n0] * DFEAT + lane], oA);
                if (act1) atomicAdd(&out[(size_t)batch[n1] * DFEAT + lane], oB);
            } else {
                h_out[(size_t)n0 * DFEAT + lane] = oA;
                if (act1) h_out[(size_t)n1 * DFEAT + lane] = oB;
            }
        }
        __syncthreads();
    }
}

// ============================================================================
extern "C" void kernel_launch(void* const* d_in, const int* in_sizes, int n_in,
                              void* d_out, int out_size, void* d_ws, size_t ws_size,
                              hipStream_t stream) {
    const float* x_raw = (const float*)d_in[0];
    const int*   eidx  = (const int*)d_in[1];
    const int*   batch = (const int*)d_in[2];
    const float* Wl0 = (const float*)d_in[3];
    const float* bl0 = (const float*)d_in[4];
    const float* Wr0 = (const float*)d_in[5];
    const float* Wl1 = (const float*)d_in[6];
    const float* bl1 = (const float*)d_in[7];
    const float* Wr1 = (const float*)d_in[8];
    const float* Wl2 = (const float*)d_in[9];
    const float* bl2 = (const float*)d_in[10];
    const float* Wr2 = (const float*)d_in[11];

    const int N = in_sizes[0] / DFEAT;
    const int E = in_sizes[1] / 2;
    const int* srcs = eidx;
    const int* dsts = eidx + E;
    float* out = (float*)d_out;

    const int nb = (N + 1023) / 1024;

    char* ws = (char*)d_ws;
    auto align512 = [](size_t v) { return (v + 511) & ~(size_t)511; };
    size_t off = 0;
    int* degi   = (int*)(ws + off); off += align512((size_t)N * 4);
    int* rowptr = (int*)(ws + off); off += align512(((size_t)N + 1) * 4);
    int* cursor = (int*)(ws + off); off += align512((size_t)N * 4);
    int* bsum   = (int*)(ws + off); off += align512((size_t)nb * 4);
    int* col    = (int*)(ws + off); off += align512((size_t)E * 4);
    float* hA   = (float*)(ws + off); off += align512((size_t)N * DFEAT * 4);
    float* hB   = (float*)(ws + off);

    hipMemsetAsync(degi, 0, (size_t)N * 4, stream);
    hipMemsetAsync(out, 0, (size_t)out_size * 4, stream);

    deg_count_kernel<<<(E + 255) / 256, 256, 0, stream>>>(dsts, degi, E);
    block_sum_kernel<<<nb, 1024, 0, stream>>>(degi, bsum, N);
    scan_bsum_kernel<<<1, 64, 0, stream>>>(bsum, nb);
    scan_final_kernel<<<nb, 1024, 0, stream>>>(degi, bsum, rowptr, cursor, N);
    fill_kernel<<<(E + 255) / 256, 256, 0, stream>>>(srcs, dsts, cursor, col, E);

    const int layerBlocks = 1024;   // 4 blocks/CU (LDS-capped), grid-stride over pairs

    sage_layer_kernel<<<layerBlocks, 256, 0, stream>>>(x_raw, rowptr, col,
        Wl0, bl0, Wr0, hA, nullptr, nullptr, N, 0);
    sage_layer_kernel<<<layerBlocks, 256, 0, stream>>>(hA, rowptr, col,
        Wl1, bl1, Wr1, hB, nullptr, nullptr, N, 0);
    sage_layer_kernel<<<layerBlocks, 256, 0, stream>>>(hB, rowptr, col,
        Wl2, bl2, Wr2, nullptr, batch, out, N, 1);
}

// Round 4
// 671.636 us; speedup vs baseline: 2.2404x; 1.0805x over previous
//
#include <hip/hip_runtime.h>

#define DFEAT 64

// ============================================================================
// CSR build (edge_index constant across layers -> build once per call)
// ============================================================================

__global__ void __launch_bounds__(256)
deg_count_kernel(const int* __restrict__ dsts, int* __restrict__ degi, int E) {
    int e = blockIdx.x * 256 + threadIdx.x;
    if (e < E) atomicAdd(&degi[dsts[e]], 1);
}

__global__ void __launch_bounds__(1024)
block_sum_kernel(const int* __restrict__ degi, int* __restrict__ bsum, int N) {
    __shared__ int sm[1024];
    int idx = blockIdx.x * 1024 + threadIdx.x;
    sm[threadIdx.x] = (idx < N) ? degi[idx] : 0;
    __syncthreads();
    for (int s = 512; s > 0; s >>= 1) {
        if (threadIdx.x < s) sm[threadIdx.x] += sm[threadIdx.x + s];
        __syncthreads();
    }
    if (threadIdx.x == 0) bsum[blockIdx.x] = sm[0];
}

__global__ void __launch_bounds__(64)
scan_bsum_kernel(int* __restrict__ bsum, int nb) {
    if (threadIdx.x == 0 && blockIdx.x == 0) {
        int run = 0;
        for (int i = 0; i < nb; ++i) { int v = bsum[i]; bsum[i] = run; run += v; }
    }
}

__global__ void __launch_bounds__(1024)
scan_final_kernel(const int* __restrict__ degi, const int* __restrict__ bsum,
                  int* __restrict__ rowptr, int* __restrict__ cursor, int N) {
    __shared__ int sm[1024];
    int idx = blockIdx.x * 1024 + threadIdx.x;
    int v = (idx < N) ? degi[idx] : 0;
    sm[threadIdx.x] = v;
    __syncthreads();
    for (int s = 1; s < 1024; s <<= 1) {
        int t = (threadIdx.x >= s) ? sm[threadIdx.x - s] : 0;
        __syncthreads();
        sm[threadIdx.x] += t;
        __syncthreads();
    }
    int excl = bsum[blockIdx.x] + sm[threadIdx.x] - v;
    if (idx < N) { rowptr[idx] = excl; cursor[idx] = excl; }
    if (idx == N - 1) rowptr[N] = excl + v;   // == E
}

__global__ void __launch_bounds__(256)
fill_kernel(const int* __restrict__ srcs, const int* __restrict__ dsts,
            int* __restrict__ cursor, int* __restrict__ col, int E) {
    int e = blockIdx.x * 256 + threadIdx.x;
    if (e < E) {
        int pos = atomicAdd(&cursor[dsts[e]], 1);
        col[pos] = srcs[e];
    }
}

// ============================================================================
// Standalone gather-mean: one wave per node, NO LDS, NO barriers -> high
// occupancy, waves free-run (R1-scatter concurrency profile).
// Lane map: r=lane>>4 (neighbor slot), c=lane&15 (float4 chunk). Neighbor
// slot i = 4k+r. All loads in a deg-tier are independent & unconditional
// (clamped index + multiply mask); deg tiers are WAVE-UNIFORM branches.
// ============================================================================
__global__ void __launch_bounds__(256)
gather_mean_kernel(const float* __restrict__ x, const int* __restrict__ rowptr,
                   const int* __restrict__ col, float* __restrict__ mean, int N) {
    int w = (blockIdx.x * 256 + threadIdx.x) >> 6;   // node id
    if (w >= N) return;
    const int lane = threadIdx.x & 63;
    const int r = lane >> 4;
    const int c = lane & 15;
    const float4* x4 = reinterpret_cast<const float4*>(x);
    float4* mean4 = reinterpret_cast<float4*>(mean);

    int st = rowptr[w], en = rowptr[w + 1];
    int deg = en - st;

    if (deg == 0) {
        if (r == 0) mean4[(size_t)w * 16 + c] = make_float4(0, 0, 0, 0);
        return;
    }

    // one coalesced col load covers the first 64 neighbor slots
    int nb = col[st + min(lane, deg - 1)];
    float4 acc = make_float4(0, 0, 0, 0);

#pragma unroll
    for (int k = 0; k < 4; ++k) {            // slots 0..15 (always)
        int i = 4 * k + r;
        int q = __shfl(nb, min(i, deg - 1), 64);
        float4 v = x4[(size_t)q * 16 + c];
        float m = (i < deg) ? 1.0f : 0.0f;
        acc.x += v.x * m; acc.y += v.y * m; acc.z += v.z * m; acc.w += v.w * m;
    }
    if (deg > 16) {                          // slots 16..31 (wave-uniform branch)
#pragma unroll
        for (int k = 4; k < 8; ++k) {
            int i = 4 * k + r;
            int q = __shfl(nb, min(i, deg - 1), 64);
            float4 v = x4[(size_t)q * 16 + c];
            float m = (i < deg) ? 1.0f : 0.0f;
            acc.x += v.x * m; acc.y += v.y * m; acc.z += v.z * m; acc.w += v.w * m;
        }
    }
    if (deg > 32) {                          // slots 32..63 (rare)
#pragma unroll
        for (int k = 8; k < 16; ++k) {
            int i = 4 * k + r;
            int q = __shfl(nb, min(i, deg - 1), 64);
            float4 v = x4[(size_t)q * 16 + c];
            float m = (i < deg) ? 1.0f : 0.0f;
            acc.x += v.x * m; acc.y += v.y * m; acc.z += v.z * m; acc.w += v.w * m;
        }
    }
    for (int base = 64; base < deg; base += 64) {   // ultra-rare tail
        int cnt = deg - base;
        int nb2 = col[st + base + min(lane, cnt - 1)];
#pragma unroll
        for (int k = 0; k < 16; ++k) {
            int i = 4 * k + r;
            int q = __shfl(nb2, min(i, cnt - 1), 64);
            float4 v = x4[(size_t)q * 16 + c];
            float m = (i < cnt) ? 1.0f : 0.0f;
            acc.x += v.x * m; acc.y += v.y * m; acc.z += v.z * m; acc.w += v.w * m;
        }
    }

    // sum across the 4 neighbor slots (lane bits 4,5)
#pragma unroll
    for (int off = 16; off <= 32; off <<= 1) {
        acc.x += __shfl_xor(acc.x, off, 64);
        acc.y += __shfl_xor(acc.y, off, 64);
        acc.z += __shfl_xor(acc.z, off, 64);
        acc.w += __shfl_xor(acc.w, off, 64);
    }
    float inv = 1.0f / (float)deg;
    if (r == 0) {
        float4 mo;
        mo.x = acc.x * inv; mo.y = acc.y * inv; mo.z = acc.z * inv; mo.w = acc.w * inv;
        mean4[(size_t)w * 16 + c] = mo;
    }
}

// ============================================================================
// Slim transform: out = mean@Wl.T + bl + x@Wr.T; L2norm; ReLU; store or
// fused batch-sum readout. One wave per node pair; weights in LDS (stride
// 68); per-iteration loads are coalesced float4 (no gather).
// ============================================================================
__global__ void __launch_bounds__(256)
transform_kernel(const float* __restrict__ x, const float* __restrict__ mean,
                 const float* __restrict__ Wl, const float* __restrict__ bl,
                 const float* __restrict__ Wr,
                 float* __restrict__ h_out,
                 const int* __restrict__ batch, float* __restrict__ out,
                 int n_nodes, int final_layer) {
    constexpr int WS = DFEAT + 4;
    __shared__ float WlL[DFEAT * WS];
    __shared__ float WrL[DFEAT * WS];
    __shared__ float feat[4][4 * DFEAT];   // [meanA | xA | meanB | xB]

    for (int t = threadIdx.x; t < DFEAT * DFEAT; t += 256) {
        int rr = t >> 6, cc = t & 63;
        WlL[rr * WS + cc] = Wl[t];
        WrL[rr * WS + cc] = Wr[t];
    }
    __syncthreads();

    const int wib  = threadIdx.x >> 6;
    const int lane = threadIdx.x & 63;
    const int g    = lane >> 4;     // 0:meanA 1:xA 2:meanB 3:xB
    const int c    = lane & 15;
    float* fm = feat[wib];
    float4* fmv = reinterpret_cast<float4*>(fm);
    const float4* x4 = reinterpret_cast<const float4*>(x);
    const float4* mean4 = reinterpret_cast<const float4*>(mean);
    const float4* wl4 = reinterpret_cast<const float4*>(&WlL[lane * WS]);
    const float4* wr4 = reinterpret_cast<const float4*>(&WrL[lane * WS]);
    const float4* fm4 = reinterpret_cast<const float4*>(fm);
    const float blv = bl[lane];

    const int P      = (n_nodes + 1) >> 1;
    const int nwaves = gridDim.x * 4;
    const int gwave  = blockIdx.x * 4 + wib;
    const int iters  = (P + nwaves - 1) / nwaves;   // uniform trip count

    for (int it = 0; it < iters; ++it) {
        int p = gwave + it * nwaves;
        bool actp = (p < P);
        int n0 = 2 * p;
        int n1 = 2 * p + 1;
        bool act1 = actp && (n1 < n_nodes);
        int n1c = act1 ? n1 : n0;

        if (actp) {
            int node = (g & 2) ? n1c : n0;
            const float4* srcp = (g & 1) ? x4 : mean4;
            fmv[lane] = srcp[(size_t)node * 16 + c];
        }
        __syncthreads();

        if (actp) {
            float accA = blv, accB = blv;
#pragma unroll
            for (int j = 0; j < DFEAT / 4; ++j) {
                float4 w1 = wl4[j];
                float4 w2 = wr4[j];
                float4 a1 = fm4[j];
                float4 a2 = fm4[16 + j];
                float4 b1 = fm4[32 + j];
                float4 b2 = fm4[48 + j];
                accA += a1.x * w1.x + a1.y * w1.y + a1.z * w1.z + a1.w * w1.w
                      + a2.x * w2.x + a2.y * w2.y + a2.z * w2.z + a2.w * w2.w;
                accB += b1.x * w1.x + b1.y * w1.y + b1.z * w1.z + b1.w * w1.w
                      + b2.x * w2.x + b2.y * w2.y + b2.z * w2.z + b2.w * w2.w;
            }
            float ssA = accA * accA, ssB = accB * accB;
#pragma unroll
            for (int off = 32; off; off >>= 1) {
                ssA += __shfl_xor(ssA, off, 64);
                ssB += __shfl_xor(ssB, off, 64);
            }
            float oA = fmaxf(accA / fmaxf(sqrtf(ssA), 1e-12f), 0.0f);
            float oB = fmaxf(accB / fmaxf(sqrtf(ssB), 1e-12f), 0.0f);

            if (final_layer) {
                atomicAdd(&out[(size_t)batch[n0] * DFEAT + lane], oA);
                if (act1) atomicAdd(&out[(size_t)batch[n1] * DFEAT + lane], oB);
            } else {
                h_out[(size_t)n0 * DFEAT + lane] = oA;
                if (act1) h_out[(size_t)n1 * DFEAT + lane] = oB;
            }
        }
        __syncthreads();
    }
}

// ============================================================================
extern "C" void kernel_launch(void* const* d_in, const int* in_sizes, int n_in,
                              void* d_out, int out_size, void* d_ws, size_t ws_size,
                              hipStream_t stream) {
    const float* x_raw = (const float*)d_in[0];
    const int*   eidx  = (const int*)d_in[1];
    const int*   batch = (const int*)d_in[2];
    const float* Wl0 = (const float*)d_in[3];
    const float* bl0 = (const float*)d_in[4];
    const float* Wr0 = (const float*)d_in[5];
    const float* Wl1 = (const float*)d_in[6];
    const float* bl1 = (const float*)d_in[7];
    const float* Wr1 = (const float*)d_in[8];
    const float* Wl2 = (const float*)d_in[9];
    const float* bl2 = (const float*)d_in[10];
    const float* Wr2 = (const float*)d_in[11];

    const int N = in_sizes[0] / DFEAT;
    const int E = in_sizes[1] / 2;
    const int* srcs = eidx;
    const int* dsts = eidx + E;
    float* out = (float*)d_out;

    const int nb = (N + 1023) / 1024;

    char* ws = (char*)d_ws;
    auto align512 = [](size_t v) { return (v + 511) & ~(size_t)511; };
    size_t off = 0;
    int* degi   = (int*)(ws + off); off += align512((size_t)N * 4);
    int* rowptr = (int*)(ws + off); off += align512(((size_t)N + 1) * 4);
    int* cursor = (int*)(ws + off); off += align512((size_t)N * 4);
    int* bsum   = (int*)(ws + off); off += align512((size_t)nb * 4);
    int* col    = (int*)(ws + off); off += align512((size_t)E * 4);
    float* meanb= (float*)(ws + off); off += align512((size_t)N * DFEAT * 4);
    float* hA   = (float*)(ws + off); off += align512((size_t)N * DFEAT * 4);
    float* hB   = (float*)(ws + off);

    hipMemsetAsync(degi, 0, (size_t)N * 4, stream);
    hipMemsetAsync(out, 0, (size_t)out_size * 4, stream);

    deg_count_kernel<<<(E + 255) / 256, 256, 0, stream>>>(dsts, degi, E);
    block_sum_kernel<<<nb, 1024, 0, stream>>>(degi, bsum, N);
    scan_bsum_kernel<<<1, 64, 0, stream>>>(bsum, nb);
    scan_final_kernel<<<nb, 1024, 0, stream>>>(degi, bsum, rowptr, cursor, N);
    fill_kernel<<<(E + 255) / 256, 256, 0, stream>>>(srcs, dsts, cursor, col, E);

    const int gatherBlocks = (N + 3) / 4;   // one wave per node
    const int xfBlocks     = 1024;          // grid-stride over node pairs

    // ---- layer 0
    gather_mean_kernel<<<gatherBlocks, 256, 0, stream>>>(x_raw, rowptr, col, meanb, N);
    transform_kernel<<<xfBlocks, 256, 0, stream>>>(x_raw, meanb, Wl0, bl0, Wr0,
                                                   hA, nullptr, nullptr, N, 0);
    // ---- layer 1
    gather_mean_kernel<<<gatherBlocks, 256, 0, stream>>>(hA, rowptr, col, meanb, N);
    transform_kernel<<<xfBlocks, 256, 0, stream>>>(hA, meanb, Wl1, bl1, Wr1,
                                                   hB, nullptr, nullptr, N, 0);
    // ---- layer 2
    gather_mean_kernel<<<gatherBlocks, 256, 0, stream>>>(hB, rowptr, col, meanb, N);
    transform_kernel<<<xfBlocks, 256, 0, stream>>>(hB, meanb, Wl2, bl2, Wr2,
                                                   nullptr, batch, out, N, 1);
}

// Round 5
// 642.766 us; speedup vs baseline: 2.3410x; 1.0449x over previous
//
#include <hip/hip_runtime.h>

#define DFEAT 64

// ---------------- bf16 helpers (OCP bfloat16, RNE pack) ----------------
__device__ __forceinline__ float bfhi(unsigned int u) {   // high 16 bits as bf16
    return __builtin_bit_cast(float, u & 0xFFFF0000u);
}
__device__ __forceinline__ float bflo(unsigned int u) {   // low 16 bits as bf16
    return __builtin_bit_cast(float, u << 16);
}
__device__ __forceinline__ unsigned short f2bf(float f) { // RNE
    unsigned int u = __builtin_bit_cast(unsigned int, f);
    u += 0x7FFFu + ((u >> 16) & 1u);
    return (unsigned short)(u >> 16);
}
__device__ __forceinline__ float4 upk4(uint2 v) {         // 4 bf16 -> 4 fp32
    float4 r;
    r.x = bflo(v.x); r.y = bfhi(v.x);
    r.z = bflo(v.y); r.w = bfhi(v.y);
    return r;
}

// ============================================================================
// fp32 -> bf16 conversion of the input features (once per call)
// ============================================================================
__global__ void __launch_bounds__(256)
cvt_bf16_kernel(const float* __restrict__ in, unsigned short* __restrict__ outb,
                int n4) {   // n4 = total elements / 4
    int i = blockIdx.x * 256 + threadIdx.x;
    if (i >= n4) return;
    const float4 v = reinterpret_cast<const float4*>(in)[i];
    uint2 p;
    p.x = (unsigned int)f2bf(v.x) | ((unsigned int)f2bf(v.y) << 16);
    p.y = (unsigned int)f2bf(v.z) | ((unsigned int)f2bf(v.w) << 16);
    reinterpret_cast<uint2*>(outb)[i] = p;
}

// ============================================================================
// CSR build (edge_index constant across layers -> build once per call)
// ============================================================================
__global__ void __launch_bounds__(256)
deg_count_kernel(const int* __restrict__ dsts, int* __restrict__ degi, int E) {
    int e = blockIdx.x * 256 + threadIdx.x;
    if (e < E) atomicAdd(&degi[dsts[e]], 1);
}

__global__ void __launch_bounds__(1024)
block_sum_kernel(const int* __restrict__ degi, int* __restrict__ bsum, int N) {
    __shared__ int sm[1024];
    int idx = blockIdx.x * 1024 + threadIdx.x;
    sm[threadIdx.x] = (idx < N) ? degi[idx] : 0;
    __syncthreads();
    for (int s = 512; s > 0; s >>= 1) {
        if (threadIdx.x < s) sm[threadIdx.x] += sm[threadIdx.x + s];
        __syncthreads();
    }
    if (threadIdx.x == 0) bsum[blockIdx.x] = sm[0];
}

__global__ void __launch_bounds__(64)
scan_bsum_kernel(int* __restrict__ bsum, int nb) {
    if (threadIdx.x == 0 && blockIdx.x == 0) {
        int run = 0;
        for (int i = 0; i < nb; ++i) { int v = bsum[i]; bsum[i] = run; run += v; }
    }
}

__global__ void __launch_bounds__(1024)
scan_final_kernel(const int* __restrict__ degi, const int* __restrict__ bsum,
                  int* __restrict__ rowptr, int* __restrict__ cursor, int N) {
    __shared__ int sm[1024];
    int idx = blockIdx.x * 1024 + threadIdx.x;
    int v = (idx < N) ? degi[idx] : 0;
    sm[threadIdx.x] = v;
    __syncthreads();
    for (int s = 1; s < 1024; s <<= 1) {
        int t = (threadIdx.x >= s) ? sm[threadIdx.x - s] : 0;
        __syncthreads();
        sm[threadIdx.x] += t;
        __syncthreads();
    }
    int excl = bsum[blockIdx.x] + sm[threadIdx.x] - v;
    if (idx < N) { rowptr[idx] = excl; cursor[idx] = excl; }
    if (idx == N - 1) rowptr[N] = excl + v;
}

__global__ void __launch_bounds__(256)
fill_kernel(const int* __restrict__ srcs, const int* __restrict__ dsts,
            int* __restrict__ cursor, int* __restrict__ col, int E) {
    int e = blockIdx.x * 256 + threadIdx.x;
    if (e < E) {
        int pos = atomicAdd(&cursor[dsts[e]], 1);
        col[pos] = srcs[e];
    }
}

// ============================================================================
// Gather-mean over bf16 feature rows (128 B each). One wave per node, no
// LDS/barriers. r=lane>>4 (neighbor slot), c=lane&15 (uint2 = 4 bf16 chunk).
// fp32 accumulate; bf16 mean out. Deg tiers are wave-uniform branches.
// ============================================================================
__global__ void __launch_bounds__(256)
gather_mean_kernel(const unsigned short* __restrict__ xb,
                   const int* __restrict__ rowptr, const int* __restrict__ col,
                   unsigned short* __restrict__ meanb, int N) {
    int w = (blockIdx.x * 256 + threadIdx.x) >> 6;
    if (w >= N) return;
    const int lane = threadIdx.x & 63;
    const int r = lane >> 4;
    const int c = lane & 15;
    const uint2* x2 = reinterpret_cast<const uint2*>(xb);
    uint2* mean2 = reinterpret_cast<uint2*>(meanb);

    int st = rowptr[w], en = rowptr[w + 1];
    int deg = en - st;

    if (deg == 0) {
        if (r == 0) mean2[(size_t)w * 16 + c] = make_uint2(0, 0);
        return;
    }

    int nb = col[st + min(lane, deg - 1)];
    float4 acc = make_float4(0, 0, 0, 0);

#pragma unroll
    for (int k = 0; k < 4; ++k) {            // slots 0..15 (always)
        int i = 4 * k + r;
        int q = __shfl(nb, min(i, deg - 1), 64);
        float4 v = upk4(x2[(size_t)q * 16 + c]);
        float m = (i < deg) ? 1.0f : 0.0f;
        acc.x += v.x * m; acc.y += v.y * m; acc.z += v.z * m; acc.w += v.w * m;
    }
    if (deg > 16) {                          // slots 16..31
#pragma unroll
        for (int k = 4; k < 8; ++k) {
            int i = 4 * k + r;
            int q = __shfl(nb, min(i, deg - 1), 64);
            float4 v = upk4(x2[(size_t)q * 16 + c]);
            float m = (i < deg) ? 1.0f : 0.0f;
            acc.x += v.x * m; acc.y += v.y * m; acc.z += v.z * m; acc.w += v.w * m;
        }
    }
    if (deg > 32) {                          // slots 32..63 (rare)
#pragma unroll
        for (int k = 8; k < 16; ++k) {
            int i = 4 * k + r;
            int q = __shfl(nb, min(i, deg - 1), 64);
            float4 v = upk4(x2[(size_t)q * 16 + c]);
            float m = (i < deg) ? 1.0f : 0.0f;
            acc.x += v.x * m; acc.y += v.y * m; acc.z += v.z * m; acc.w += v.w * m;
        }
    }
    for (int base = 64; base < deg; base += 64) {   // ultra-rare tail
        int cnt = deg - base;
        int nb2 = col[st + base + min(lane, cnt - 1)];
#pragma unroll
        for (int k = 0; k < 16; ++k) {
            int i = 4 * k + r;
            int q = __shfl(nb2, min(i, cnt - 1), 64);
            float4 v = upk4(x2[(size_t)q * 16 + c]);
            float m = (i < cnt) ? 1.0f : 0.0f;
            acc.x += v.x * m; acc.y += v.y * m; acc.z += v.z * m; acc.w += v.w * m;
        }
    }

#pragma unroll
    for (int off = 16; off <= 32; off <<= 1) {
        acc.x += __shfl_xor(acc.x, off, 64);
        acc.y += __shfl_xor(acc.y, off, 64);
        acc.z += __shfl_xor(acc.z, off, 64);
        acc.w += __shfl_xor(acc.w, off, 64);
    }
    float inv = 1.0f / (float)deg;
    if (r == 0) {
        uint2 p;
        p.x = (unsigned int)f2bf(acc.x * inv) | ((unsigned int)f2bf(acc.y * inv) << 16);
        p.y = (unsigned int)f2bf(acc.z * inv) | ((unsigned int)f2bf(acc.w * inv) << 16);
        mean2[(size_t)w * 16 + c] = p;
    }
}

// ============================================================================
// Transform: out = mean@Wl.T + bl + x@Wr.T; L2norm; ReLU.
// bf16 mean/x in (converted to fp32 at LDS-stage time), fp32 weights in LDS,
// bf16 h out (or fp32 atomic batch-sum readout for the final layer).
// ============================================================================
__global__ void __launch_bounds__(256)
transform_kernel(const unsigned short* __restrict__ xb,
                 const unsigned short* __restrict__ meanb,
                 const float* __restrict__ Wl, const float* __restrict__ bl,
                 const float* __restrict__ Wr,
                 unsigned short* __restrict__ h_out,
                 const int* __restrict__ batch, float* __restrict__ out,
                 int n_nodes, int final_layer) {
    constexpr int WS = DFEAT + 4;
    __shared__ float WlL[DFEAT * WS];
    __shared__ float WrL[DFEAT * WS];
    __shared__ float feat[4][4 * DFEAT];   // [meanA | xA | meanB | xB] as fp32

    for (int t = threadIdx.x; t < DFEAT * DFEAT; t += 256) {
        int rr = t >> 6, cc = t & 63;
        WlL[rr * WS + cc] = Wl[t];
        WrL[rr * WS + cc] = Wr[t];
    }
    __syncthreads();

    const int wib  = threadIdx.x >> 6;
    const int lane = threadIdx.x & 63;
    const int g    = lane >> 4;     // 0:meanA 1:xA 2:meanB 3:xB
    const int c    = lane & 15;
    float* fm = feat[wib];
    float4* fmv = reinterpret_cast<float4*>(fm);
    const uint2* x2 = reinterpret_cast<const uint2*>(xb);
    const uint2* mean2 = reinterpret_cast<const uint2*>(meanb);
    const float4* wl4 = reinterpret_cast<const float4*>(&WlL[lane * WS]);
    const float4* wr4 = reinterpret_cast<const float4*>(&WrL[lane * WS]);
    const float4* fm4 = reinterpret_cast<const float4*>(fm);
    const float blv = bl[lane];

    const int P      = (n_nodes + 1) >> 1;
    const int nwaves = gridDim.x * 4;
    const int gwave  = blockIdx.x * 4 + wib;
    const int iters  = (P + nwaves - 1) / nwaves;   // uniform trip count

    for (int it = 0; it < iters; ++it) {
        int p = gwave + it * nwaves;
        bool actp = (p < P);
        int n0 = 2 * p;
        int n1 = 2 * p + 1;
        bool act1 = actp && (n1 < n_nodes);
        int n1c = act1 ? n1 : n0;

        if (actp) {
            int node = (g & 2) ? n1c : n0;
            const uint2* srcp = (g & 1) ? x2 : mean2;
            fmv[lane] = upk4(srcp[(size_t)node * 16 + c]);
        }
        __syncthreads();

        if (actp) {
            float accA = blv, accB = blv;
#pragma unroll
            for (int j = 0; j < DFEAT / 4; ++j) {
                float4 w1 = wl4[j];
                float4 w2 = wr4[j];
                float4 a1 = fm4[j];
                float4 a2 = fm4[16 + j];
                float4 b1 = fm4[32 + j];
                float4 b2 = fm4[48 + j];
                accA += a1.x * w1.x + a1.y * w1.y + a1.z * w1.z + a1.w * w1.w
                      + a2.x * w2.x + a2.y * w2.y + a2.z * w2.z + a2.w * w2.w;
                accB += b1.x * w1.x + b1.y * w1.y + b1.z * w1.z + b1.w * w1.w
                      + b2.x * w2.x + b2.y * w2.y + b2.z * w2.z + b2.w * w2.w;
            }
            float ssA = accA * accA, ssB = accB * accB;
#pragma unroll
            for (int off = 32; off; off >>= 1) {
                ssA += __shfl_xor(ssA, off, 64);
                ssB += __shfl_xor(ssB, off, 64);
            }
            float oA = fmaxf(accA / fmaxf(sqrtf(ssA), 1e-12f), 0.0f);
            float oB = fmaxf(accB / fmaxf(sqrtf(ssB), 1e-12f), 0.0f);

            if (final_layer) {
                atomicAdd(&out[(size_t)batch[n0] * DFEAT + lane], oA);
                if (act1) atomicAdd(&out[(size_t)batch[n1] * DFEAT + lane], oB);
            } else {
                h_out[(size_t)n0 * DFEAT + lane] = f2bf(oA);
                if (act1) h_out[(size_t)n1 * DFEAT + lane] = f2bf(oB);
            }
        }
        __syncthreads();
    }
}

// ============================================================================
extern "C" void kernel_launch(void* const* d_in, const int* in_sizes, int n_in,
                              void* d_out, int out_size, void* d_ws, size_t ws_size,
                              hipStream_t stream) {
    const float* x_raw = (const float*)d_in[0];
    const int*   eidx  = (const int*)d_in[1];
    const int*   batch = (const int*)d_in[2];
    const float* Wl0 = (const float*)d_in[3];
    const float* bl0 = (const float*)d_in[4];
    const float* Wr0 = (const float*)d_in[5];
    const float* Wl1 = (const float*)d_in[6];
    const float* bl1 = (const float*)d_in[7];
    const float* Wr1 = (const float*)d_in[8];
    const float* Wl2 = (const float*)d_in[9];
    const float* bl2 = (const float*)d_in[10];
    const float* Wr2 = (const float*)d_in[11];

    const int N = in_sizes[0] / DFEAT;
    const int E = in_sizes[1] / 2;
    const int* srcs = eidx;
    const int* dsts = eidx + E;
    float* out = (float*)d_out;

    const int nb = (N + 1023) / 1024;

    char* ws = (char*)d_ws;
    auto align512 = [](size_t v) { return (v + 511) & ~(size_t)511; };
    size_t off = 0;
    int* degi   = (int*)(ws + off); off += align512((size_t)N * 4);
    int* rowptr = (int*)(ws + off); off += align512(((size_t)N + 1) * 4);
    int* cursor = (int*)(ws + off); off += align512((size_t)N * 4);
    int* bsum   = (int*)(ws + off); off += align512((size_t)nb * 4);
    int* col    = (int*)(ws + off); off += align512((size_t)E * 4);
    unsigned short* xb    = (unsigned short*)(ws + off); off += align512((size_t)N * DFEAT * 2);
    unsigned short* meanb = (unsigned short*)(ws + off); off += align512((size_t)N * DFEAT * 2);
    unsigned short* hA    = (unsigned short*)(ws + off); off += align512((size_t)N * DFEAT * 2);
    unsigned short* hB    = (unsigned short*)(ws + off);

    hipMemsetAsync(degi, 0, (size_t)N * 4, stream);
    hipMemsetAsync(out, 0, (size_t)out_size * 4, stream);

    // input fp32 -> bf16 (once)
    const int n4 = N * DFEAT / 4;
    cvt_bf16_kernel<<<(n4 + 255) / 256, 256, 0, stream>>>(x_raw, xb, n4);

    // CSR build (once)
    deg_count_kernel<<<(E + 255) / 256, 256, 0, stream>>>(dsts, degi, E);
    block_sum_kernel<<<nb, 1024, 0, stream>>>(degi, bsum, N);
    scan_bsum_kernel<<<1, 64, 0, stream>>>(bsum, nb);
    scan_final_kernel<<<nb, 1024, 0, stream>>>(degi, bsum, rowptr, cursor, N);
    fill_kernel<<<(E + 255) / 256, 256, 0, stream>>>(srcs, dsts, cursor, col, E);

    const int gatherBlocks = (N + 3) / 4;
    const int xfBlocks     = 1024;

    // ---- layer 0
    gather_mean_kernel<<<gatherBlocks, 256, 0, stream>>>(xb, rowptr, col, meanb, N);
    transform_kernel<<<xfBlocks, 256, 0, stream>>>(xb, meanb, Wl0, bl0, Wr0,
                                                   hA, nullptr, nullptr, N, 0);
    // ---- layer 1
    gather_mean_kernel<<<gatherBlocks, 256, 0, stream>>>(hA, rowptr, col, meanb, N);
    transform_kernel<<<xfBlocks, 256, 0, stream>>>(hA, meanb, Wl1, bl1, Wr1,
                                                   hB, nullptr, nullptr, N, 0);
    // ---- layer 2
    gather_mean_kernel<<<gatherBlocks, 256, 0, stream>>>(hB, rowptr, col, meanb, N);
    transform_kernel<<<xfBlocks, 256, 0, stream>>>(hB, meanb, Wl2, bl2, Wr2,
                                                   nullptr, batch, out, N, 1);
}